// Round 1
// baseline (208.372 us; speedup 1.0000x reference)
//
#include <hip/hip_runtime.h>
#include <hip/hip_bf16.h>

using bf16 = __hip_bfloat16;
typedef __attribute__((ext_vector_type(8))) short short8;
typedef __attribute__((ext_vector_type(4))) short s4v;
typedef __attribute__((ext_vector_type(4))) float float4v;
typedef __attribute__((ext_vector_type(4))) float f32x4;

#define MFMA16(a, b, c) __builtin_amdgcn_mfma_f32_16x16x32_bf16((a), (b), (c), 0, 0, 0)

// async global->LDS, 16B per lane, dest = wave-uniform base + lane*16
#define GLD_LDS16(g, l)                                            \
    __builtin_amdgcn_global_load_lds(                              \
        (const __attribute__((address_space(1))) void*)(g),        \
        (__attribute__((address_space(3))) void*)(l), 16, 0, 0)

constexpr int Bc = 2;
constexpr int Sc = 2048;
constexpr int Hc = 16;
constexpr int DKc = 64;
constexpr int Dc = 1024;
constexpr size_t MEG = 1024 * 1024;

union BFU { bf16 h; short s; };

__device__ inline short bfbits(float f) {
    BFU u; u.h = __float2bfloat16(f); return u.s;
}

__device__ inline short8 load_cvt8(const float* __restrict__ p) {
    f32x4 a = *(const f32x4*)p;
    f32x4 b = *(const f32x4*)(p + 4);
    short8 r;
    r[0] = bfbits(a[0]); r[1] = bfbits(a[1]); r[2] = bfbits(a[2]); r[3] = bfbits(a[3]);
    r[4] = bfbits(b[0]); r[5] = bfbits(b[1]); r[6] = bfbits(b[2]); r[7] = bfbits(b[3]);
    return r;
}

// ---------------------------------------------------------------------------
// One-shot fp32 -> bf16 conversion of x, Wq, Wk, Wv, Wo (8M elems) into ws.
// ---------------------------------------------------------------------------
__global__ __launch_bounds__(256) void cvt_kernel(
    const float* __restrict__ x, const float* __restrict__ Wq,
    const float* __restrict__ Wk, const float* __restrict__ Wv,
    const float* __restrict__ Wo, bf16* __restrict__ dst)
{
    const size_t i = ((size_t)blockIdx.x * 256 + threadIdx.x) * 8;
    const float* s;
    if      (i < 4 * MEG) s = x  + i;
    else if (i < 5 * MEG) s = Wq + (i - 4 * MEG);
    else if (i < 6 * MEG) s = Wk + (i - 5 * MEG);
    else if (i < 7 * MEG) s = Wv + (i - 6 * MEG);
    else                  s = Wo + (i - 7 * MEG);
    *(short8*)(dst + i) = load_cvt8(s);
}

// ---------------------------------------------------------------------------
// Fused QKV projection, m97-style BK=32. grid (24, 32): sel = bx>>3,
// ntile = bx&7. Q pre-scaled by (1/8)*log2e. V^T stores packed to 8B.
// ---------------------------------------------------------------------------
__global__ __launch_bounds__(256) void qkv_gemm_kernel(
    const bf16* __restrict__ x,
    const bf16* __restrict__ Wq, const float* __restrict__ bq,
    const bf16* __restrict__ Wk, const float* __restrict__ bk,
    const bf16* __restrict__ Wv, const float* __restrict__ bv,
    bf16* __restrict__ q_ws, bf16* __restrict__ k_ws, bf16* __restrict__ v_ws)
{
    constexpr int BM = 128, BN = 128, BK = 32;
    __shared__ __align__(16) bf16 sA[BM * BK];
    __shared__ __align__(16) bf16 sB[BN * BK];

    const int bx = blockIdx.x;
    const int sel = bx >> 3;               // 0=Q 1=K 2=V
    const int n0 = (bx & 7) * BN;
    const int m0 = blockIdx.y * BM;

    const bf16* __restrict__ Wsel = (sel == 0) ? Wq : ((sel == 1) ? Wk : Wv);
    const float* __restrict__ bsel = (sel == 0) ? bq : ((sel == 1) ? bk : bv);

    const int t = threadIdx.x;
    const int lane = t & 63;
    const int wave = t >> 6;
    const int ln = lane & 15;
    const int qd = lane >> 4;
    const int wm = (wave >> 1) * 64;
    const int wn = (wave & 1) * 64;

    const int gr = lane >> 2;              // 0..15: row within 16-row chunk
    const int gc = (lane & 3) * 8;         // 0,8,16,24

    float4v acc[4][4];
#pragma unroll
    for (int i = 0; i < 4; i++)
#pragma unroll
        for (int j = 0; j < 4; j++) acc[i][j] = (float4v)0.0f;

    for (int kk = 0; kk < Dc; kk += BK) {
        __syncthreads();
#pragma unroll
        for (int cc = 0; cc < 2; cc++) {
            const int c = wave * 2 + cc;
            GLD_LDS16(x    + (size_t)(m0 + c * 16 + gr) * Dc + kk + gc, &sA[c * 512]);
            GLD_LDS16(Wsel + (size_t)(n0 + c * 16 + gr) * Dc + kk + gc, &sB[c * 512]);
        }
        __syncthreads();

        short8 af[4], wf[4];
#pragma unroll
        for (int i = 0; i < 4; i++)
            af[i] = *(const short8*)&sA[(wm + i * 16 + ln) * BK + qd * 8];
#pragma unroll
        for (int j = 0; j < 4; j++)
            wf[j] = *(const short8*)&sB[(wn + j * 16 + ln) * BK + qd * 8];
#pragma unroll
        for (int i = 0; i < 4; i++)
#pragma unroll
            for (int j = 0; j < 4; j++)
                acc[i][j] = MFMA16(af[i], wf[j], acc[i][j]);
    }

    constexpr float QSCALE = 0.125f * 1.44269504088896f;

#pragma unroll
    for (int j = 0; j < 4; j++) {
        const int n = n0 + wn + j * 16 + ln;
        const float bias = bsel[n];
        const int h_ = n >> 6, d_ = n & 63;
#pragma unroll
        for (int i = 0; i < 4; i++) {
            const int mbase = m0 + wm + i * 16 + qd * 4;
            if (sel == 2) {                // V^T: 4 s-contiguous -> one 8B store
                const int b_ = mbase >> 11, s_ = mbase & 2047;
                s4v pk;
#pragma unroll
                for (int r = 0; r < 4; r++)
                    pk[r] = bfbits(acc[i][j][r] + bias);
                *(s4v*)&v_ws[(((size_t)(b_ * Hc + h_)) * DKc + d_) * Sc + s_] = pk;
            } else {
#pragma unroll
                for (int r = 0; r < 4; r++) {
                    const int m = mbase + r;
                    const int b_ = m >> 11, s_ = m & 2047;
                    float v = acc[i][j][r] + bias;
                    if (sel == 0) v *= QSCALE;
                    const bf16 o = __float2bfloat16(v);
                    if (sel == 0)
                        q_ws[(((size_t)(b_ * Hc + h_)) * Sc + s_) * DKc + d_] = o;
                    else
                        k_ws[(((size_t)(b_ * Hc + h_)) * Sc + s_) * DKc + d_] = o;
                }
            }
        }
    }
}

// ---------------------------------------------------------------------------
// Flash attention v5: LDS-traffic-targeted restructure. 4 waves x 32 q-rows
// (same 128-row Q tile) halves the K/V LDS read amplification per q-row:
// each wave still ingests the full 64x64 K and V tiles per ktile, but only
// 4 waves (not 8) do so per 128 q-rows. Q B-frags hoisted to registers
// (loaded from global once; kills sQ and its per-ktile re-reads). LDS drops
// 68.6 -> 51 KB => 3 blocks/CU (12 waves). Async dbuf K/V staging (xor
// swizzle, 0 conflicts), ONE barrier/ktile, swapped-operand QK^T,
// ones-column denominator. grid (32 bh, 16 qt), block 256.
// ---------------------------------------------------------------------------
__global__ __launch_bounds__(256) void attn_kernel(
    const bf16* __restrict__ q_ws, const bf16* __restrict__ k_ws,
    const bf16* __restrict__ v_ws, bf16* __restrict__ ao_ws)
{
    constexpr int LQP = 76;  // short row stride for sP
    __shared__ __align__(16) bf16 sK[2][64 * 64];    // swizzled dbuf
    __shared__ __align__(16) bf16 sV[2][64 * 64];    // V^T [d][key], swizzled dbuf
    __shared__ __align__(16) short sP[4][32 * LQP];  // per-wave P [qrow][key]

    const int bh = blockIdx.x;
    const int qt = blockIdx.y;
    const int t = threadIdx.x;
    const int lane = t & 63;
    const int wave = t >> 6;               // 0..3
    const int ln = lane & 15;
    const int qd = lane >> 4;
    short* const sPw = sP[wave];

    const bf16* __restrict__ Qbase = q_ws + (size_t)bh * Sc * DKc + qt * 128 * DKc;
    const bf16* __restrict__ Kbase = k_ws + (size_t)bh * Sc * DKc;
    const bf16* __restrict__ Vbase = v_ws + (size_t)bh * DKc * Sc;

    const int rloc = lane >> 3;            // 0..7 row within 8-row chunk
    const int blk = lane & 7;              // LDS 16B-block index

    // Q B-frags direct global->register, loop-invariant (16 VGPRs).
    // B-frag: lane holds Q[qrow = w*32 + nt*16 + ln][k = ks*32 + qd*8 .. +7]
    short8 qf[2][2];
#pragma unroll
    for (int nt = 0; nt < 2; nt++)
#pragma unroll
        for (int ks = 0; ks < 2; ks++)
            qf[nt][ks] = *(const short8*)
                (Qbase + (size_t)(wave * 32 + nt * 16 + ln) * DKc + ks * 32 + qd * 8);

    {   // stage K/V tile 0 async: 8 chunks each, two per wave
#pragma unroll
        for (int cc = 0; cc < 2; cc++) {
            const int c = wave * 2 + cc;
            const int row = c * 8 + rloc;
            const int gb = blk ^ (row & 7);
            GLD_LDS16(Kbase + (size_t)row * DKc + gb * 8, &sK[0][c * 512]);
            GLD_LDS16(Vbase + (size_t)row * Sc + gb * 8, &sV[0][c * 512]);
        }
    }

    // constant ones B-frag: B[n][k]=1 iff ln==0 (denominator column)
    short8 ones8;
    {
        const short ob = (ln == 0) ? (short)0x3F80 : (short)0;
#pragma unroll
        for (int i = 0; i < 8; i++) ones8[i] = ob;
    }

    float4v oacc[2][4];
    float4v den[2];
#pragma unroll
    for (int mt = 0; mt < 2; mt++) {
        den[mt] = (float4v)0.0f;
#pragma unroll
        for (int j = 0; j < 4; j++) oacc[mt][j] = (float4v)0.0f;
    }

    for (int kt = 0; kt < Sc / 64; kt++) {
        const int cur = kt & 1;
        __syncthreads();   // drains vmcnt: buf[cur] ready; prior reads done
        if (kt + 1 < Sc / 64) {    // prefetch next tile into the other buffer
            const int nxt = (kt + 1) & 1;
#pragma unroll
            for (int cc = 0; cc < 2; cc++) {
                const int c = wave * 2 + cc;
                const int row = c * 8 + rloc;
                const int gb = blk ^ (row & 7);
                GLD_LDS16(Kbase + (size_t)((kt + 1) * 64 + row) * DKc + gb * 8,
                          &sK[nxt][c * 512]);
                GLD_LDS16(Vbase + (size_t)row * Sc + (kt + 1) * 64 + gb * 8,
                          &sV[nxt][c * 512]);
            }
        }

        // S^T = K Q^T: A=K[m=key], B=Q[n=qrow]; C col=qrow(ln), row=key(qd*4+r)
        float4v sacc[2][4];
#pragma unroll
        for (int nt = 0; nt < 2; nt++)
#pragma unroll
            for (int m = 0; m < 4; m++) sacc[nt][m] = (float4v)0.0f;
#pragma unroll
        for (int ks = 0; ks < 2; ks++) {
#pragma unroll
            for (int m = 0; m < 4; m++) {
                const int row = m * 16 + ln;
                const short8 ak = *(const short8*)
                    &sK[cur][row * 64 + (((ks * 4 + qd) ^ (row & 7)) << 3)];
                sacc[0][m] = MFMA16(ak, qf[0][ks], sacc[0][m]);
                sacc[1][m] = MFMA16(ak, qf[1][ks], sacc[1][m]);
            }
        }

        // P = exp2(S^T) -> sP [qrow][key]: lane holds qrow=nt*16+ln, keys 4-contig.
#pragma unroll
        for (int nt = 0; nt < 2; nt++)
#pragma unroll
            for (int m = 0; m < 4; m++) {
                s4v pk;
#pragma unroll
                for (int r = 0; r < 4; r++)
                    pk[r] = bfbits(exp2f(sacc[nt][m][r]));
                *(s4v*)&sPw[(nt * 16 + ln) * LQP + m * 16 + qd * 4] = pk;
            }

        // O += P V: A=P[m=qrow], B=V^T[n=d]; ones-frag accumulates denominator.
#pragma unroll
        for (int ks = 0; ks < 2; ks++) {
            short8 ap[2];
#pragma unroll
            for (int mt = 0; mt < 2; mt++) {
                const s4v p0 = *(const s4v*)
                    &sPw[(mt * 16 + ln) * LQP + ks * 32 + qd * 8];
                const s4v p1 = *(const s4v*)
                    &sPw[(mt * 16 + ln) * LQP + ks * 32 + qd * 8 + 4];
                ap[mt][0] = p0[0]; ap[mt][1] = p0[1];
                ap[mt][2] = p0[2]; ap[mt][3] = p0[3];
                ap[mt][4] = p1[0]; ap[mt][5] = p1[1];
                ap[mt][6] = p1[2]; ap[mt][7] = p1[3];
            }
#pragma unroll
            for (int j = 0; j < 4; j++) {
                const int row = j * 16 + ln;
                const short8 bv_ = *(const short8*)
                    &sV[cur][row * 64 + (((ks * 4 + qd) ^ (row & 7)) << 3)];
                oacc[0][j] = MFMA16(ap[0], bv_, oacc[0][j]);
                oacc[1][j] = MFMA16(ap[1], bv_, oacc[1][j]);
            }
            den[0] = MFMA16(ap[0], ones8, den[0]);
            den[1] = MFMA16(ap[1], ones8, den[1]);
        }
    }

    // denominator = col n=64 => lane (qd*16); broadcast within quad.
    const int b_ = bh >> 4, h_ = bh & 15;
#pragma unroll
    for (int mt = 0; mt < 2; mt++)
#pragma unroll
        for (int r = 0; r < 4; r++) {
            const float l = __shfl(den[mt][r], lane & 48, 64);
            const float inv = 1.0f / l;
            const int s_ = qt * 128 + wave * 32 + mt * 16 + qd * 4 + r;
#pragma unroll
            for (int j = 0; j < 4; j++) {
                const int d_ = j * 16 + ln;
                ao_ws[(((size_t)(b_ * Sc + s_)) * Hc + h_) * DKc + d_] =
                    __float2bfloat16(oacc[mt][j][r] * inv);
            }
        }
}

// ---------------------------------------------------------------------------
// Output projection, m97-style BK=32. grid (8, 32), block 256.
// ---------------------------------------------------------------------------
__global__ __launch_bounds__(256) void out_gemm_kernel(
    const bf16* __restrict__ A, const bf16* __restrict__ Wo,
    const float* __restrict__ bo, float* __restrict__ out)
{
    constexpr int BM = 128, BN = 128, BK = 32;
    __shared__ __align__(16) bf16 sA[BM * BK];
    __shared__ __align__(16) bf16 sB[BN * BK];

    const int n0 = blockIdx.x * BN;
    const int m0 = blockIdx.y * BM;

    const int t = threadIdx.x;
    const int lane = t & 63;
    const int wave = t >> 6;
    const int ln = lane & 15;
    const int qd = lane >> 4;
    const int wm = (wave >> 1) * 64;
    const int wn = (wave & 1) * 64;

    const int gr = lane >> 2;
    const int gc = (lane & 3) * 8;

    float4v acc[4][4];
#pragma unroll
    for (int i = 0; i < 4; i++)
#pragma unroll
        for (int j = 0; j < 4; j++) acc[i][j] = (float4v)0.0f;

    for (int kk = 0; kk < Dc; kk += BK) {
        __syncthreads();
#pragma unroll
        for (int cc = 0; cc < 2; cc++) {
            const int c = wave * 2 + cc;
            GLD_LDS16(A  + (size_t)(m0 + c * 16 + gr) * Dc + kk + gc, &sA[c * 512]);
            GLD_LDS16(Wo + (size_t)(n0 + c * 16 + gr) * Dc + kk + gc, &sB[c * 512]);
        }
        __syncthreads();

        short8 af[4], wf[4];
#pragma unroll
        for (int i = 0; i < 4; i++)
            af[i] = *(const short8*)&sA[(wm + i * 16 + ln) * BK + qd * 8];
#pragma unroll
        for (int j = 0; j < 4; j++)
            wf[j] = *(const short8*)&sB[(wn + j * 16 + ln) * BK + qd * 8];
#pragma unroll
        for (int i = 0; i < 4; i++)
#pragma unroll
            for (int j = 0; j < 4; j++)
                acc[i][j] = MFMA16(af[i], wf[j], acc[i][j]);
    }

#pragma unroll
    for (int j = 0; j < 4; j++) {
        const int n = n0 + wn + j * 16 + ln;
        const float bias = bo[n];
#pragma unroll
        for (int i = 0; i < 4; i++) {
            const int mbase = m0 + wm + i * 16 + qd * 4;
#pragma unroll
            for (int r = 0; r < 4; r++) {
                const int m = mbase + r;
                out[(size_t)m * Dc + n] = acc[i][j][r] + bias;
            }
        }
    }
}

// ---------------------------------------------------------------------------
extern "C" void kernel_launch(void* const* d_in, const int* in_sizes, int n_in,
                              void* d_out, int out_size, void* d_ws, size_t ws_size,
                              hipStream_t stream)
{
    const float* x  = (const float*)d_in[0];
    const float* Wq = (const float*)d_in[1];
    const float* bq = (const float*)d_in[2];
    const float* Wk = (const float*)d_in[3];
    const float* bk = (const float*)d_in[4];
    const float* Wv = (const float*)d_in[5];
    const float* bv = (const float*)d_in[6];
    const float* Wo = (const float*)d_in[7];
    const float* bo = (const float*)d_in[8];
    float* out = (float*)d_out;

    bf16* base  = (bf16*)d_ws;
    bf16* q_ws  = base;                      // (b,h,s,d), pre-scaled
    bf16* k_ws  = base + 4 * MEG;            // (b,h,s,d)
    bf16* v_ws  = base + 8 * MEG;            // (b,h,d,s)  transposed
    bf16* ao_ws = base + 12 * MEG;           // (b,s,h,d) == (4096,1024)
    bf16* xb    = base + 16 * MEG;           // bf16 copies of inputs
    bf16* wqb   = base + 20 * MEG;
    bf16* wkb   = base + 21 * MEG;
    bf16* wvb   = base + 22 * MEG;
    bf16* wob   = base + 23 * MEG;

    cvt_kernel<<<dim3(4096), 256, 0, stream>>>(x, Wq, Wk, Wv, Wo, xb);
    qkv_gemm_kernel<<<dim3(24, 32), 256, 0, stream>>>(
        xb, wqb, bq, wkb, bk, wvb, bv, q_ws, k_ws, v_ws);
    attn_kernel<<<dim3(32, 16), 256, 0, stream>>>(q_ws, k_ws, v_ws, ao_ws);
    out_gemm_kernel<<<dim3(8, 32), 256, 0, stream>>>(ao_ws, wob, bo, out);
}

// Round 3
// 200.568 us; speedup vs baseline: 1.0389x; 1.0389x over previous
//
#include <hip/hip_runtime.h>
#include <hip/hip_bf16.h>

using bf16 = __hip_bfloat16;
typedef __attribute__((ext_vector_type(8))) short short8;
typedef __attribute__((ext_vector_type(4))) short s4v;
typedef __attribute__((ext_vector_type(4))) float float4v;
typedef __attribute__((ext_vector_type(4))) float f32x4;

#define MFMA16(a, b, c) __builtin_amdgcn_mfma_f32_16x16x32_bf16((a), (b), (c), 0, 0, 0)

// async global->LDS, 16B per lane, dest = wave-uniform base + lane*16
#define GLD_LDS16(g, l)                                            \
    __builtin_amdgcn_global_load_lds(                              \
        (const __attribute__((address_space(1))) void*)(g),        \
        (__attribute__((address_space(3))) void*)(l), 16, 0, 0)

constexpr int Bc = 2;
constexpr int Sc = 2048;
constexpr int Hc = 16;
constexpr int DKc = 64;
constexpr int Dc = 1024;
constexpr size_t MEG = 1024 * 1024;

union BFU { bf16 h; short s; };

__device__ inline short bfbits(float f) {
    BFU u; u.h = __float2bfloat16(f); return u.s;
}

__device__ inline short8 load_cvt8(const float* __restrict__ p) {
    f32x4 a = *(const f32x4*)p;
    f32x4 b = *(const f32x4*)(p + 4);
    short8 r;
    r[0] = bfbits(a[0]); r[1] = bfbits(a[1]); r[2] = bfbits(a[2]); r[3] = bfbits(a[3]);
    r[4] = bfbits(b[0]); r[5] = bfbits(b[1]); r[6] = bfbits(b[2]); r[7] = bfbits(b[3]);
    return r;
}

// ---------------------------------------------------------------------------
// One-shot fp32 -> bf16 conversion of x, Wq, Wk, Wv, Wo (8M elems) into ws.
// ---------------------------------------------------------------------------
__global__ __launch_bounds__(256) void cvt_kernel(
    const float* __restrict__ x, const float* __restrict__ Wq,
    const float* __restrict__ Wk, const float* __restrict__ Wv,
    const float* __restrict__ Wo, bf16* __restrict__ dst)
{
    const size_t i = ((size_t)blockIdx.x * 256 + threadIdx.x) * 8;
    const float* s;
    if      (i < 4 * MEG) s = x  + i;
    else if (i < 5 * MEG) s = Wq + (i - 4 * MEG);
    else if (i < 6 * MEG) s = Wk + (i - 5 * MEG);
    else if (i < 7 * MEG) s = Wv + (i - 6 * MEG);
    else                  s = Wo + (i - 7 * MEG);
    *(short8*)(dst + i) = load_cvt8(s);
}

// ---------------------------------------------------------------------------
// Fused QKV projection, m97-style BK=32. grid (24, 32): sel = bx>>3,
// ntile = bx&7. Q pre-scaled by (1/8)*log2e. V^T stores packed to 8B.
// ---------------------------------------------------------------------------
__global__ __launch_bounds__(256) void qkv_gemm_kernel(
    const bf16* __restrict__ x,
    const bf16* __restrict__ Wq, const float* __restrict__ bq,
    const bf16* __restrict__ Wk, const float* __restrict__ bk,
    const bf16* __restrict__ Wv, const float* __restrict__ bv,
    bf16* __restrict__ q_ws, bf16* __restrict__ k_ws, bf16* __restrict__ v_ws)
{
    constexpr int BM = 128, BN = 128, BK = 32;
    __shared__ __align__(16) bf16 sA[BM * BK];
    __shared__ __align__(16) bf16 sB[BN * BK];

    const int bx = blockIdx.x;
    const int sel = bx >> 3;               // 0=Q 1=K 2=V
    const int n0 = (bx & 7) * BN;
    const int m0 = blockIdx.y * BM;

    const bf16* __restrict__ Wsel = (sel == 0) ? Wq : ((sel == 1) ? Wk : Wv);
    const float* __restrict__ bsel = (sel == 0) ? bq : ((sel == 1) ? bk : bv);

    const int t = threadIdx.x;
    const int lane = t & 63;
    const int wave = t >> 6;
    const int ln = lane & 15;
    const int qd = lane >> 4;
    const int wm = (wave >> 1) * 64;
    const int wn = (wave & 1) * 64;

    const int gr = lane >> 2;              // 0..15: row within 16-row chunk
    const int gc = (lane & 3) * 8;         // 0,8,16,24

    float4v acc[4][4];
#pragma unroll
    for (int i = 0; i < 4; i++)
#pragma unroll
        for (int j = 0; j < 4; j++) acc[i][j] = (float4v)0.0f;

    for (int kk = 0; kk < Dc; kk += BK) {
        __syncthreads();
#pragma unroll
        for (int cc = 0; cc < 2; cc++) {
            const int c = wave * 2 + cc;
            GLD_LDS16(x    + (size_t)(m0 + c * 16 + gr) * Dc + kk + gc, &sA[c * 512]);
            GLD_LDS16(Wsel + (size_t)(n0 + c * 16 + gr) * Dc + kk + gc, &sB[c * 512]);
        }
        __syncthreads();

        short8 af[4], wf[4];
#pragma unroll
        for (int i = 0; i < 4; i++)
            af[i] = *(const short8*)&sA[(wm + i * 16 + ln) * BK + qd * 8];
#pragma unroll
        for (int j = 0; j < 4; j++)
            wf[j] = *(const short8*)&sB[(wn + j * 16 + ln) * BK + qd * 8];
#pragma unroll
        for (int i = 0; i < 4; i++)
#pragma unroll
            for (int j = 0; j < 4; j++)
                acc[i][j] = MFMA16(af[i], wf[j], acc[i][j]);
    }

    constexpr float QSCALE = 0.125f * 1.44269504088896f;

#pragma unroll
    for (int j = 0; j < 4; j++) {
        const int n = n0 + wn + j * 16 + ln;
        const float bias = bsel[n];
        const int h_ = n >> 6, d_ = n & 63;
#pragma unroll
        for (int i = 0; i < 4; i++) {
            const int mbase = m0 + wm + i * 16 + qd * 4;
            if (sel == 2) {                // V^T: 4 s-contiguous -> one 8B store
                const int b_ = mbase >> 11, s_ = mbase & 2047;
                s4v pk;
#pragma unroll
                for (int r = 0; r < 4; r++)
                    pk[r] = bfbits(acc[i][j][r] + bias);
                *(s4v*)&v_ws[(((size_t)(b_ * Hc + h_)) * DKc + d_) * Sc + s_] = pk;
            } else {
#pragma unroll
                for (int r = 0; r < 4; r++) {
                    const int m = mbase + r;
                    const int b_ = m >> 11, s_ = m & 2047;
                    float v = acc[i][j][r] + bias;
                    if (sel == 0) v *= QSCALE;
                    const bf16 o = __float2bfloat16(v);
                    if (sel == 0)
                        q_ws[(((size_t)(b_ * Hc + h_)) * Sc + s_) * DKc + d_] = o;
                    else
                        k_ws[(((size_t)(b_ * Hc + h_)) * Sc + s_) * DKc + d_] = o;
                }
            }
        }
    }
}

// ---------------------------------------------------------------------------
// Flash attention v6: back to the v4 512-thread shape (8 waves x 16 q-rows,
// 16 waves/CU — Round-1 showed TLP, not LDS bandwidth, is what binds).
// Per-wave issue-overhead cuts, wave count untouched:
//   - Q hoisted to registers (loaded once from global; sQ buffer deleted,
//     2 ds_read_b128 + addressing removed per ktile). LDS 68.6 -> 50 KB.
//   - sP row stride 76 -> 72 shorts (144 B, 16B-aligned rows): PV A-frag is
//     ONE aligned ds_read_b128, replacing 2x ds_read_b64 + 16 short inserts
//     (pure-VALU fragment assembly was a big slice of the 53% VALUBusy).
//   - s_setprio(1) around both MFMA clusters (T5).
// Async dbuf K/V staging (xor swizzle, 0 conflicts), ONE barrier/ktile,
// swapped-operand QK^T, ones-column denominator. grid (32,16), block 512.
// ---------------------------------------------------------------------------
__global__ __launch_bounds__(512) void attn_kernel(
    const bf16* __restrict__ q_ws, const bf16* __restrict__ k_ws,
    const bf16* __restrict__ v_ws, bf16* __restrict__ ao_ws)
{
    constexpr int LQP = 72;  // short row stride for sP (144 B, 16B-aligned)
    __shared__ __align__(16) bf16 sK[2][64 * 64];    // swizzled dbuf
    __shared__ __align__(16) bf16 sV[2][64 * 64];    // V^T [d][key], swizzled dbuf
    __shared__ __align__(16) short sP[8][16 * LQP];  // per-wave P [qrow][key]

    const int bh = blockIdx.x;
    const int qt = blockIdx.y;
    const int t = threadIdx.x;
    const int lane = t & 63;
    const int wave = t >> 6;               // 0..7
    const int ln = lane & 15;
    const int qd = lane >> 4;
    short* const sPw = sP[wave];

    const bf16* __restrict__ Qbase = q_ws + (size_t)bh * Sc * DKc + qt * 128 * DKc;
    const bf16* __restrict__ Kbase = k_ws + (size_t)bh * Sc * DKc;
    const bf16* __restrict__ Vbase = v_ws + (size_t)bh * DKc * Sc;

    const int rloc = lane >> 3;            // 0..7 row within 8-row chunk
    const int blk = lane & 7;              // LDS 16B-block index

    // Q B-frags direct global->register, loop-invariant (8 VGPRs).
    // lane holds Q[qrow = wave*16 + ln][k = ks*32 + qd*8 .. +7]
    short8 qf[2];
#pragma unroll
    for (int ks = 0; ks < 2; ks++)
        qf[ks] = *(const short8*)
            (Qbase + (size_t)(wave * 16 + ln) * DKc + ks * 32 + qd * 8);

    {   // stage K/V tile 0 async: 8 chunks each, one per wave
        const int row = wave * 8 + rloc;
        const int gb = blk ^ (row & 7);
        GLD_LDS16(Kbase + (size_t)row * DKc + gb * 8, &sK[0][wave * 512]);
        GLD_LDS16(Vbase + (size_t)row * Sc + gb * 8, &sV[0][wave * 512]);
    }

    // constant ones B-frag: B[n=64+ln][k]=1 iff ln==0 (denominator column)
    short8 ones8;
    {
        const short ob = (ln == 0) ? (short)0x3F80 : (short)0;
#pragma unroll
        for (int i = 0; i < 8; i++) ones8[i] = ob;
    }

    float4v oacc[5];
#pragma unroll
    for (int j = 0; j < 5; j++) oacc[j] = (float4v)0.0f;

    for (int kt = 0; kt < Sc / 64; kt++) {
        const int cur = kt & 1;
        __syncthreads();   // drains vmcnt: buf[cur] ready; prior reads done
        if (kt + 1 < Sc / 64) {    // prefetch next tile into the other buffer
            const int nxt = (kt + 1) & 1;
            const int row = wave * 8 + rloc;
            const int gb = blk ^ (row & 7);
            GLD_LDS16(Kbase + (size_t)((kt + 1) * 64 + row) * DKc + gb * 8,
                      &sK[nxt][wave * 512]);
            GLD_LDS16(Vbase + (size_t)row * Sc + (kt + 1) * 64 + gb * 8,
                      &sV[nxt][wave * 512]);
        }

        // S^T = K Q^T: A=K[m=key], B=Q[n=qrow]; C col=qrow(ln), row=key(qd*4+r)
        float4v sacc[4];
#pragma unroll
        for (int j = 0; j < 4; j++) sacc[j] = (float4v)0.0f;
        __builtin_amdgcn_s_setprio(1);
#pragma unroll
        for (int ks = 0; ks < 2; ks++) {
#pragma unroll
            for (int j = 0; j < 4; j++) {
                const int row = j * 16 + ln;
                const short8 ak = *(const short8*)
                    &sK[cur][row * 64 + (((ks * 4 + qd) ^ (row & 7)) << 3)];
                sacc[j] = MFMA16(ak, qf[ks], sacc[j]);
            }
        }
        __builtin_amdgcn_s_setprio(0);

        // P = exp2(S^T) -> sP [qrow][key]: lane holds qrow=ln, keys 4-contig.
#pragma unroll
        for (int j = 0; j < 4; j++) {
            s4v pk;
#pragma unroll
            for (int r = 0; r < 4; r++)
                pk[r] = bfbits(exp2f(sacc[j][r]));
            *(s4v*)&sPw[ln * LQP + j * 16 + qd * 4] = pk;
        }

        // O += P V: A=P[m=qrow], B=V^T[n=d]; ones-frag accumulates denominator.
        __builtin_amdgcn_s_setprio(1);
#pragma unroll
        for (int ks = 0; ks < 2; ks++) {
            // direct 16B read: keys [ks*32 + qd*8, +8) of row ln
            const short8 ap = *(const short8*)&sPw[ln * LQP + ks * 32 + qd * 8];
#pragma unroll
            for (int j = 0; j < 4; j++) {
                const int row = j * 16 + ln;
                const short8 bv_ = *(const short8*)
                    &sV[cur][row * 64 + (((ks * 4 + qd) ^ (row & 7)) << 3)];
                oacc[j] = MFMA16(ap, bv_, oacc[j]);
            }
            oacc[4] = MFMA16(ap, ones8, oacc[4]);
        }
        __builtin_amdgcn_s_setprio(0);
    }

    // denominator = col n=64 => lane (qd*16); broadcast within quad.
    const int b_ = bh >> 4, h_ = bh & 15;
#pragma unroll
    for (int r = 0; r < 4; r++) {
        const float l = __shfl(oacc[4][r], lane & 48, 64);
        const float inv = 1.0f / l;
        const int s_ = qt * 128 + wave * 16 + qd * 4 + r;
#pragma unroll
        for (int j = 0; j < 4; j++) {
            const int d_ = j * 16 + ln;
            ao_ws[(((size_t)(b_ * Sc + s_)) * Hc + h_) * DKc + d_] =
                __float2bfloat16(oacc[j][r] * inv);
        }
    }
}

// ---------------------------------------------------------------------------
// Output projection, m97-style BK=32. grid (8, 32), block 256.
// ---------------------------------------------------------------------------
__global__ __launch_bounds__(256) void out_gemm_kernel(
    const bf16* __restrict__ A, const bf16* __restrict__ Wo,
    const float* __restrict__ bo, float* __restrict__ out)
{
    constexpr int BM = 128, BN = 128, BK = 32;
    __shared__ __align__(16) bf16 sA[BM * BK];
    __shared__ __align__(16) bf16 sB[BN * BK];

    const int n0 = blockIdx.x * BN;
    const int m0 = blockIdx.y * BM;

    const int t = threadIdx.x;
    const int lane = t & 63;
    const int wave = t >> 6;
    const int ln = lane & 15;
    const int qd = lane >> 4;
    const int wm = (wave >> 1) * 64;
    const int wn = (wave & 1) * 64;

    const int gr = lane >> 2;
    const int gc = (lane & 3) * 8;

    float4v acc[4][4];
#pragma unroll
    for (int i = 0; i < 4; i++)
#pragma unroll
        for (int j = 0; j < 4; j++) acc[i][j] = (float4v)0.0f;

    for (int kk = 0; kk < Dc; kk += BK) {
        __syncthreads();
#pragma unroll
        for (int cc = 0; cc < 2; cc++) {
            const int c = wave * 2 + cc;
            GLD_LDS16(A  + (size_t)(m0 + c * 16 + gr) * Dc + kk + gc, &sA[c * 512]);
            GLD_LDS16(Wo + (size_t)(n0 + c * 16 + gr) * Dc + kk + gc, &sB[c * 512]);
        }
        __syncthreads();

        short8 af[4], wf[4];
#pragma unroll
        for (int i = 0; i < 4; i++)
            af[i] = *(const short8*)&sA[(wm + i * 16 + ln) * BK + qd * 8];
#pragma unroll
        for (int j = 0; j < 4; j++)
            wf[j] = *(const short8*)&sB[(wn + j * 16 + ln) * BK + qd * 8];
#pragma unroll
        for (int i = 0; i < 4; i++)
#pragma unroll
            for (int j = 0; j < 4; j++)
                acc[i][j] = MFMA16(af[i], wf[j], acc[i][j]);
    }

#pragma unroll
    for (int j = 0; j < 4; j++) {
        const int n = n0 + wn + j * 16 + ln;
        const float bias = bo[n];
#pragma unroll
        for (int i = 0; i < 4; i++) {
            const int mbase = m0 + wm + i * 16 + qd * 4;
#pragma unroll
            for (int r = 0; r < 4; r++) {
                const int m = mbase + r;
                out[(size_t)m * Dc + n] = acc[i][j][r] + bias;
            }
        }
    }
}

// ---------------------------------------------------------------------------
extern "C" void kernel_launch(void* const* d_in, const int* in_sizes, int n_in,
                              void* d_out, int out_size, void* d_ws, size_t ws_size,
                              hipStream_t stream)
{
    const float* x  = (const float*)d_in[0];
    const float* Wq = (const float*)d_in[1];
    const float* bq = (const float*)d_in[2];
    const float* Wk = (const float*)d_in[3];
    const float* bk = (const float*)d_in[4];
    const float* Wv = (const float*)d_in[5];
    const float* bv = (const float*)d_in[6];
    const float* Wo = (const float*)d_in[7];
    const float* bo = (const float*)d_in[8];
    float* out = (float*)d_out;

    bf16* base  = (bf16*)d_ws;
    bf16* q_ws  = base;                      // (b,h,s,d), pre-scaled
    bf16* k_ws  = base + 4 * MEG;            // (b,h,s,d)
    bf16* v_ws  = base + 8 * MEG;            // (b,h,d,s)  transposed
    bf16* ao_ws = base + 12 * MEG;           // (b,s,h,d) == (4096,1024)
    bf16* xb    = base + 16 * MEG;           // bf16 copies of inputs
    bf16* wqb   = base + 20 * MEG;
    bf16* wkb   = base + 21 * MEG;
    bf16* wvb   = base + 22 * MEG;
    bf16* wob   = base + 23 * MEG;

    cvt_kernel<<<dim3(4096), 256, 0, stream>>>(x, Wq, Wk, Wv, Wo, xb);
    qkv_gemm_kernel<<<dim3(24, 32), 256, 0, stream>>>(
        xb, wqb, bq, wkb, bk, wvb, bv, q_ws, k_ws, v_ws);
    attn_kernel<<<dim3(32, 16), 512, 0, stream>>>(q_ws, k_ws, v_ws, ao_ws);
    out_gemm_kernel<<<dim3(8, 32), 256, 0, stream>>>(ao_ws, wob, bo, out);
}

// Round 4
// 198.151 us; speedup vs baseline: 1.0516x; 1.0122x over previous
//
#include <hip/hip_runtime.h>
#include <hip/hip_bf16.h>

using bf16 = __hip_bfloat16;
typedef __attribute__((ext_vector_type(8))) short short8;
typedef __attribute__((ext_vector_type(4))) short s4v;
typedef __attribute__((ext_vector_type(4))) float float4v;
typedef __attribute__((ext_vector_type(4))) float f32x4;

#define MFMA16(a, b, c) __builtin_amdgcn_mfma_f32_16x16x32_bf16((a), (b), (c), 0, 0, 0)

// async global->LDS, 16B per lane, dest = wave-uniform base + lane*16
#define GLD_LDS16(g, l)                                            \
    __builtin_amdgcn_global_load_lds(                              \
        (const __attribute__((address_space(1))) void*)(g),        \
        (__attribute__((address_space(3))) void*)(l), 16, 0, 0)

constexpr int Bc = 2;
constexpr int Sc = 2048;
constexpr int Hc = 16;
constexpr int DKc = 64;
constexpr int Dc = 1024;
constexpr size_t MEG = 1024 * 1024;

union BFU { bf16 h; short s; };

__device__ inline short bfbits(float f) {
    BFU u; u.h = __float2bfloat16(f); return u.s;
}

__device__ inline short8 load_cvt8(const float* __restrict__ p) {
    f32x4 a = *(const f32x4*)p;
    f32x4 b = *(const f32x4*)(p + 4);
    short8 r;
    r[0] = bfbits(a[0]); r[1] = bfbits(a[1]); r[2] = bfbits(a[2]); r[3] = bfbits(a[3]);
    r[4] = bfbits(b[0]); r[5] = bfbits(b[1]); r[6] = bfbits(b[2]); r[7] = bfbits(b[3]);
    return r;
}

// ---------------------------------------------------------------------------
// One-shot fp32 -> bf16 conversion of x, Wq, Wk, Wv, Wo (8M elems) into ws.
// ---------------------------------------------------------------------------
__global__ __launch_bounds__(256) void cvt_kernel(
    const float* __restrict__ x, const float* __restrict__ Wq,
    const float* __restrict__ Wk, const float* __restrict__ Wv,
    const float* __restrict__ Wo, bf16* __restrict__ dst)
{
    const size_t i = ((size_t)blockIdx.x * 256 + threadIdx.x) * 8;
    const float* s;
    if      (i < 4 * MEG) s = x  + i;
    else if (i < 5 * MEG) s = Wq + (i - 4 * MEG);
    else if (i < 6 * MEG) s = Wk + (i - 5 * MEG);
    else if (i < 7 * MEG) s = Wv + (i - 6 * MEG);
    else                  s = Wo + (i - 7 * MEG);
    *(short8*)(dst + i) = load_cvt8(s);
}

// ---------------------------------------------------------------------------
// Fused QKV projection, m97-style BK=32. grid (24, 32): sel = bx>>3,
// ntile = bx&7. Q pre-scaled by (1/8)*log2e. V^T stores packed to 8B.
// ---------------------------------------------------------------------------
__global__ __launch_bounds__(256) void qkv_gemm_kernel(
    const bf16* __restrict__ x,
    const bf16* __restrict__ Wq, const float* __restrict__ bq,
    const bf16* __restrict__ Wk, const float* __restrict__ bk,
    const bf16* __restrict__ Wv, const float* __restrict__ bv,
    bf16* __restrict__ q_ws, bf16* __restrict__ k_ws, bf16* __restrict__ v_ws)
{
    constexpr int BM = 128, BN = 128, BK = 32;
    __shared__ __align__(16) bf16 sA[BM * BK];
    __shared__ __align__(16) bf16 sB[BN * BK];

    const int bx = blockIdx.x;
    const int sel = bx >> 3;               // 0=Q 1=K 2=V
    const int n0 = (bx & 7) * BN;
    const int m0 = blockIdx.y * BM;

    const bf16* __restrict__ Wsel = (sel == 0) ? Wq : ((sel == 1) ? Wk : Wv);
    const float* __restrict__ bsel = (sel == 0) ? bq : ((sel == 1) ? bk : bv);

    const int t = threadIdx.x;
    const int lane = t & 63;
    const int wave = t >> 6;
    const int ln = lane & 15;
    const int qd = lane >> 4;
    const int wm = (wave >> 1) * 64;
    const int wn = (wave & 1) * 64;

    const int gr = lane >> 2;              // 0..15: row within 16-row chunk
    const int gc = (lane & 3) * 8;         // 0,8,16,24

    float4v acc[4][4];
#pragma unroll
    for (int i = 0; i < 4; i++)
#pragma unroll
        for (int j = 0; j < 4; j++) acc[i][j] = (float4v)0.0f;

    for (int kk = 0; kk < Dc; kk += BK) {
        __syncthreads();
#pragma unroll
        for (int cc = 0; cc < 2; cc++) {
            const int c = wave * 2 + cc;
            GLD_LDS16(x    + (size_t)(m0 + c * 16 + gr) * Dc + kk + gc, &sA[c * 512]);
            GLD_LDS16(Wsel + (size_t)(n0 + c * 16 + gr) * Dc + kk + gc, &sB[c * 512]);
        }
        __syncthreads();

        short8 af[4], wf[4];
#pragma unroll
        for (int i = 0; i < 4; i++)
            af[i] = *(const short8*)&sA[(wm + i * 16 + ln) * BK + qd * 8];
#pragma unroll
        for (int j = 0; j < 4; j++)
            wf[j] = *(const short8*)&sB[(wn + j * 16 + ln) * BK + qd * 8];
#pragma unroll
        for (int i = 0; i < 4; i++)
#pragma unroll
            for (int j = 0; j < 4; j++)
                acc[i][j] = MFMA16(af[i], wf[j], acc[i][j]);
    }

    constexpr float QSCALE = 0.125f * 1.44269504088896f;

#pragma unroll
    for (int j = 0; j < 4; j++) {
        const int n = n0 + wn + j * 16 + ln;
        const float bias = bsel[n];
        const int h_ = n >> 6, d_ = n & 63;
#pragma unroll
        for (int i = 0; i < 4; i++) {
            const int mbase = m0 + wm + i * 16 + qd * 4;
            if (sel == 2) {                // V^T: 4 s-contiguous -> one 8B store
                const int b_ = mbase >> 11, s_ = mbase & 2047;
                s4v pk;
#pragma unroll
                for (int r = 0; r < 4; r++)
                    pk[r] = bfbits(acc[i][j][r] + bias);
                *(s4v*)&v_ws[(((size_t)(b_ * Hc + h_)) * DKc + d_) * Sc + s_] = pk;
            } else {
#pragma unroll
                for (int r = 0; r < 4; r++) {
                    const int m = mbase + r;
                    const int b_ = m >> 11, s_ = m & 2047;
                    float v = acc[i][j][r] + bias;
                    if (sel == 0) v *= QSCALE;
                    const bf16 o = __float2bfloat16(v);
                    if (sel == 0)
                        q_ws[(((size_t)(b_ * Hc + h_)) * Sc + s_) * DKc + d_] = o;
                    else
                        k_ws[(((size_t)(b_ * Hc + h_)) * Sc + s_) * DKc + d_] = o;
                }
            }
        }
    }
}

// ---------------------------------------------------------------------------
// Flash attention v7: v6 with the two diagnosed fixes.
//   - sP row stride back to 76 shorts (152 B): 6*ln mod 32 start-banks tile
//     all 32 banks -> 0 conflicts (v6's 72 caused 3.1M: all offsets mult-of-4
//     dwords -> 8 spans only). PV A-frag = two b64 loads + shufflevector
//     concat (no VALU inserts; register pairing).
//   - __launch_bounds__(512, 4): true occupancy target (LDS caps at 2
//     blocks/CU = 4 waves/SIMD) -> VGPR cap 128 (v6: 40) so the compiler can
//     hoist the 16 loop-invariant swizzled LDS addresses + pipeline exp/cvt.
// Kept from v6: Q in registers (sQ deleted), setprio around MFMA clusters.
// Async dbuf K/V staging (xor swizzle), ONE barrier/ktile, swapped-operand
// QK^T, ones-column denominator. grid (32,16), block 512.
// ---------------------------------------------------------------------------
__global__ __launch_bounds__(512, 4) void attn_kernel(
    const bf16* __restrict__ q_ws, const bf16* __restrict__ k_ws,
    const bf16* __restrict__ v_ws, bf16* __restrict__ ao_ws)
{
    constexpr int LQP = 76;  // short row stride for sP (152 B, conflict-free)
    __shared__ __align__(16) bf16 sK[2][64 * 64];    // swizzled dbuf
    __shared__ __align__(16) bf16 sV[2][64 * 64];    // V^T [d][key], swizzled dbuf
    __shared__ __align__(16) short sP[8][16 * LQP];  // per-wave P [qrow][key]

    const int bh = blockIdx.x;
    const int qt = blockIdx.y;
    const int t = threadIdx.x;
    const int lane = t & 63;
    const int wave = t >> 6;               // 0..7
    const int ln = lane & 15;
    const int qd = lane >> 4;
    short* const sPw = sP[wave];

    const bf16* __restrict__ Qbase = q_ws + (size_t)bh * Sc * DKc + qt * 128 * DKc;
    const bf16* __restrict__ Kbase = k_ws + (size_t)bh * Sc * DKc;
    const bf16* __restrict__ Vbase = v_ws + (size_t)bh * DKc * Sc;

    const int rloc = lane >> 3;            // 0..7 row within 8-row chunk
    const int blk = lane & 7;              // LDS 16B-block index

    // Q B-frags direct global->register, loop-invariant (8 VGPRs).
    // lane holds Q[qrow = wave*16 + ln][k = ks*32 + qd*8 .. +7]
    short8 qf[2];
#pragma unroll
    for (int ks = 0; ks < 2; ks++)
        qf[ks] = *(const short8*)
            (Qbase + (size_t)(wave * 16 + ln) * DKc + ks * 32 + qd * 8);

    {   // stage K/V tile 0 async: 8 chunks each, one per wave
        const int row = wave * 8 + rloc;
        const int gb = blk ^ (row & 7);
        GLD_LDS16(Kbase + (size_t)row * DKc + gb * 8, &sK[0][wave * 512]);
        GLD_LDS16(Vbase + (size_t)row * Sc + gb * 8, &sV[0][wave * 512]);
    }

    // constant ones B-frag: B[n=64+ln][k]=1 iff ln==0 (denominator column)
    short8 ones8;
    {
        const short ob = (ln == 0) ? (short)0x3F80 : (short)0;
#pragma unroll
        for (int i = 0; i < 8; i++) ones8[i] = ob;
    }

    float4v oacc[5];
#pragma unroll
    for (int j = 0; j < 5; j++) oacc[j] = (float4v)0.0f;

    for (int kt = 0; kt < Sc / 64; kt++) {
        const int cur = kt & 1;
        __syncthreads();   // drains vmcnt: buf[cur] ready; prior reads done
        if (kt + 1 < Sc / 64) {    // prefetch next tile into the other buffer
            const int nxt = (kt + 1) & 1;
            const int row = wave * 8 + rloc;
            const int gb = blk ^ (row & 7);
            GLD_LDS16(Kbase + (size_t)((kt + 1) * 64 + row) * DKc + gb * 8,
                      &sK[nxt][wave * 512]);
            GLD_LDS16(Vbase + (size_t)row * Sc + (kt + 1) * 64 + gb * 8,
                      &sV[nxt][wave * 512]);
        }

        // S^T = K Q^T: A=K[m=key], B=Q[n=qrow]; C col=qrow(ln), row=key(qd*4+r)
        float4v sacc[4];
#pragma unroll
        for (int j = 0; j < 4; j++) sacc[j] = (float4v)0.0f;
        __builtin_amdgcn_s_setprio(1);
#pragma unroll
        for (int ks = 0; ks < 2; ks++) {
#pragma unroll
            for (int j = 0; j < 4; j++) {
                const int row = j * 16 + ln;
                const short8 ak = *(const short8*)
                    &sK[cur][row * 64 + (((ks * 4 + qd) ^ (row & 7)) << 3)];
                sacc[j] = MFMA16(ak, qf[ks], sacc[j]);
            }
        }
        __builtin_amdgcn_s_setprio(0);

        // P = exp2(S^T) -> sP [qrow][key]: lane holds qrow=ln, keys 4-contig.
#pragma unroll
        for (int j = 0; j < 4; j++) {
            s4v pk;
#pragma unroll
            for (int r = 0; r < 4; r++)
                pk[r] = bfbits(exp2f(sacc[j][r]));
            *(s4v*)&sPw[ln * LQP + j * 16 + qd * 4] = pk;
        }

        // O += P V: A=P[m=qrow], B=V^T[n=d]; ones-frag accumulates denominator.
        __builtin_amdgcn_s_setprio(1);
#pragma unroll
        for (int ks = 0; ks < 2; ks++) {
            // two b64 reads -> register-pair concat (no element inserts)
            const s4v p0 = *(const s4v*)&sPw[ln * LQP + ks * 32 + qd * 8];
            const s4v p1 = *(const s4v*)&sPw[ln * LQP + ks * 32 + qd * 8 + 4];
            const short8 ap = __builtin_shufflevector(p0, p1, 0, 1, 2, 3, 4, 5, 6, 7);
#pragma unroll
            for (int j = 0; j < 4; j++) {
                const int row = j * 16 + ln;
                const short8 bv_ = *(const short8*)
                    &sV[cur][row * 64 + (((ks * 4 + qd) ^ (row & 7)) << 3)];
                oacc[j] = MFMA16(ap, bv_, oacc[j]);
            }
            oacc[4] = MFMA16(ap, ones8, oacc[4]);
        }
        __builtin_amdgcn_s_setprio(0);
    }

    // denominator = col n=64 => lane (qd*16); broadcast within quad.
    const int b_ = bh >> 4, h_ = bh & 15;
#pragma unroll
    for (int r = 0; r < 4; r++) {
        const float l = __shfl(oacc[4][r], lane & 48, 64);
        const float inv = 1.0f / l;
        const int s_ = qt * 128 + wave * 16 + qd * 4 + r;
#pragma unroll
        for (int j = 0; j < 4; j++) {
            const int d_ = j * 16 + ln;
            ao_ws[(((size_t)(b_ * Sc + s_)) * Hc + h_) * DKc + d_] =
                __float2bfloat16(oacc[j][r] * inv);
        }
    }
}

// ---------------------------------------------------------------------------
// Output projection, m97-style BK=32. grid (8, 32), block 256.
// ---------------------------------------------------------------------------
__global__ __launch_bounds__(256) void out_gemm_kernel(
    const bf16* __restrict__ A, const bf16* __restrict__ Wo,
    const float* __restrict__ bo, float* __restrict__ out)
{
    constexpr int BM = 128, BN = 128, BK = 32;
    __shared__ __align__(16) bf16 sA[BM * BK];
    __shared__ __align__(16) bf16 sB[BN * BK];

    const int n0 = blockIdx.x * BN;
    const int m0 = blockIdx.y * BM;

    const int t = threadIdx.x;
    const int lane = t & 63;
    const int wave = t >> 6;
    const int ln = lane & 15;
    const int qd = lane >> 4;
    const int wm = (wave >> 1) * 64;
    const int wn = (wave & 1) * 64;

    const int gr = lane >> 2;
    const int gc = (lane & 3) * 8;

    float4v acc[4][4];
#pragma unroll
    for (int i = 0; i < 4; i++)
#pragma unroll
        for (int j = 0; j < 4; j++) acc[i][j] = (float4v)0.0f;

    for (int kk = 0; kk < Dc; kk += BK) {
        __syncthreads();
#pragma unroll
        for (int cc = 0; cc < 2; cc++) {
            const int c = wave * 2 + cc;
            GLD_LDS16(A  + (size_t)(m0 + c * 16 + gr) * Dc + kk + gc, &sA[c * 512]);
            GLD_LDS16(Wo + (size_t)(n0 + c * 16 + gr) * Dc + kk + gc, &sB[c * 512]);
        }
        __syncthreads();

        short8 af[4], wf[4];
#pragma unroll
        for (int i = 0; i < 4; i++)
            af[i] = *(const short8*)&sA[(wm + i * 16 + ln) * BK + qd * 8];
#pragma unroll
        for (int j = 0; j < 4; j++)
            wf[j] = *(const short8*)&sB[(wn + j * 16 + ln) * BK + qd * 8];
#pragma unroll
        for (int i = 0; i < 4; i++)
#pragma unroll
            for (int j = 0; j < 4; j++)
                acc[i][j] = MFMA16(af[i], wf[j], acc[i][j]);
    }

#pragma unroll
    for (int j = 0; j < 4; j++) {
        const int n = n0 + wn + j * 16 + ln;
        const float bias = bo[n];
#pragma unroll
        for (int i = 0; i < 4; i++) {
            const int mbase = m0 + wm + i * 16 + qd * 4;
#pragma unroll
            for (int r = 0; r < 4; r++) {
                const int m = mbase + r;
                out[(size_t)m * Dc + n] = acc[i][j][r] + bias;
            }
        }
    }
}

// ---------------------------------------------------------------------------
extern "C" void kernel_launch(void* const* d_in, const int* in_sizes, int n_in,
                              void* d_out, int out_size, void* d_ws, size_t ws_size,
                              hipStream_t stream)
{
    const float* x  = (const float*)d_in[0];
    const float* Wq = (const float*)d_in[1];
    const float* bq = (const float*)d_in[2];
    const float* Wk = (const float*)d_in[3];
    const float* bk = (const float*)d_in[4];
    const float* Wv = (const float*)d_in[5];
    const float* bv = (const float*)d_in[6];
    const float* Wo = (const float*)d_in[7];
    const float* bo = (const float*)d_in[8];
    float* out = (float*)d_out;

    bf16* base  = (bf16*)d_ws;
    bf16* q_ws  = base;                      // (b,h,s,d), pre-scaled
    bf16* k_ws  = base + 4 * MEG;            // (b,h,s,d)
    bf16* v_ws  = base + 8 * MEG;            // (b,h,d,s)  transposed
    bf16* ao_ws = base + 12 * MEG;           // (b,s,h,d) == (4096,1024)
    bf16* xb    = base + 16 * MEG;           // bf16 copies of inputs
    bf16* wqb   = base + 20 * MEG;
    bf16* wkb   = base + 21 * MEG;
    bf16* wvb   = base + 22 * MEG;
    bf16* wob   = base + 23 * MEG;

    cvt_kernel<<<dim3(4096), 256, 0, stream>>>(x, Wq, Wk, Wv, Wo, xb);
    qkv_gemm_kernel<<<dim3(24, 32), 256, 0, stream>>>(
        xb, wqb, bq, wkb, bk, wvb, bv, q_ws, k_ws, v_ws);
    attn_kernel<<<dim3(32, 16), 512, 0, stream>>>(q_ws, k_ws, v_ws, ao_ws);
    out_gemm_kernel<<<dim3(8, 32), 256, 0, stream>>>(ao_ws, wob, bo, out);
}